// Round 7
// baseline (1203.869 us; speedup 1.0000x reference)
//
#include <hip/hip_runtime.h>

#define EDGES 200000
#define NATOMS 100000
#define NMOLS 2000
#define H 128
#define MAXNB 15
#define AFD 18
#define INFD 23
#define CSTRIDE 136  // C-tile LDS row stride (bf16): +8 pad

typedef unsigned short bf16s;
typedef __attribute__((ext_vector_type(8))) short short8;
typedef __attribute__((ext_vector_type(4))) float f32x4;

__device__ inline float bf2f(bf16s u) {
  union { unsigned int i; float f; } c; c.i = ((unsigned int)u) << 16; return c.f;
}
__device__ inline bf16s f2bf(float f) {
  union { float f; unsigned int i; } c; c.f = f;
  unsigned int lsb = (c.i >> 16) & 1u;
  c.i += 0x7fffu + lsb;              // round-to-nearest-even
  return (bf16s)(c.i >> 16);
}
__device__ inline void load4(const bf16s* p, float v[4]) {
  ushort4 t = *(const ushort4*)p;
  v[0] = bf2f(t.x); v[1] = bf2f(t.y); v[2] = bf2f(t.z); v[3] = bf2f(t.w);
}
__device__ inline void store4(bf16s* p, const float v[4]) {
  ushort4 t; t.x = f2bf(v[0]); t.y = f2bf(v[1]); t.z = f2bf(v[2]); t.w = f2bf(v[3]);
  *(ushort4*)p = t;
}

// ---- binput = fbonds @ W_i ; message = relu(binput). Last 2 blocks also
// ---- build bf16-transposed weights Wt[n][k] for W_h / W_o[AFD:,:].
__global__ __launch_bounds__(256) void k_binput(
    const float* __restrict__ fbonds, const float* __restrict__ Wi,
    bf16s* __restrict__ binput, bf16s* __restrict__ message,
    const float* __restrict__ Wh, const float* __restrict__ Wo,
    bf16s* __restrict__ wt_h, bf16s* __restrict__ wt_o) {
  if (blockIdx.x >= EDGES / 8) {
    const int which = blockIdx.x - EDGES / 8;
    const float* S = which ? (Wo + AFD * H) : Wh;
    bf16s* D = which ? wt_o : wt_h;
    for (int i = threadIdx.x; i < H * H; i += 256) {
      int k = i >> 7, n = i & 127;
      D[n * H + k] = f2bf(S[i]);
    }
    return;
  }
  __shared__ float Wl[INFD * H];
  const int tid = threadIdx.x;
  for (int i = tid; i < INFD * H; i += 256) Wl[i] = Wi[i];
  __syncthreads();
  const int lane = tid & 31;
  const int e = blockIdx.x * 8 + (tid >> 5);
  const float* fb = &fbonds[(size_t)e * INFD];
  float acc[4] = {0.f, 0.f, 0.f, 0.f};
#pragma unroll
  for (int k = 0; k < INFD; ++k) {
    float f = fb[k];
    float4 w = *(const float4*)&Wl[k * H + lane * 4];
    acc[0] = fmaf(f, w.x, acc[0]); acc[1] = fmaf(f, w.y, acc[1]);
    acc[2] = fmaf(f, w.z, acc[2]); acc[3] = fmaf(f, w.w, acc[3]);
  }
  store4(&binput[(size_t)e * H + lane * 4], acc);
  float r[4] = {fmaxf(acc[0], 0.f), fmaxf(acc[1], 0.f),
                fmaxf(acc[2], 0.f), fmaxf(acc[3], 0.f)};
  store4(&message[(size_t)e * H + lane * 4], r);
}

// ---------------- C[E,128] = A[E,128] @ W, MFMA bf16 ----------------
// MFMA from global (A rows coalesced, Wt L1-resident); C staged in LDS then
// written as contiguous 16-B stores (replaces 32 scalar 2-B stores/lane).
__global__ __launch_bounds__(256) void k_gemm_mfma(
    const bf16s* __restrict__ A, const bf16s* __restrict__ Wt,
    bf16s* __restrict__ C) {
  __shared__ bf16s Csh[64 * CSTRIDE];
  const int tid = threadIdx.x;
  const int wave = tid >> 6;
  const int lane = tid & 63;
  const int m = lane & 15;
  const int quad = lane >> 4;
  const int row0 = blockIdx.x * 64;

  f32x4 acc[8];
#pragma unroll
  for (int i = 0; i < 8; ++i) acc[i] = (f32x4){0.f, 0.f, 0.f, 0.f};

  const bf16s* Ap = A + (size_t)(row0 + wave * 16 + m) * H + quad * 8;
  const bf16s* Wp = Wt + (size_t)m * H + quad * 8;

#pragma unroll
  for (int kk = 0; kk < 4; ++kk) {
    short8 af = *(const short8*)(Ap + kk * 32);
#pragma unroll
    for (int nt = 0; nt < 8; ++nt) {
      short8 bfr = *(const short8*)(Wp + (size_t)(nt * 16) * H + kk * 32);
      acc[nt] = __builtin_amdgcn_mfma_f32_16x16x32_bf16(af, bfr, acc[nt], 0, 0, 0);
    }
  }
  const int rloc = wave * 16 + quad * 4;
#pragma unroll
  for (int nt = 0; nt < 8; ++nt) {
#pragma unroll
    for (int i = 0; i < 4; ++i) {
      Csh[(rloc + i) * CSTRIDE + nt * 16 + m] = f2bf(acc[nt][i]);
    }
  }
  __syncthreads();
  const int row = tid >> 2, q = tid & 3;   // 64 rows x 4 quarters of 32 bf16
  const bf16s* src = &Csh[row * CSTRIDE + q * 32];
  bf16s* dst = &C[(size_t)(row0 + row) * H + q * 32];
#pragma unroll
  for (int u = 0; u < 4; ++u)
    *(short8*)(dst + u * 8) = *(const short8*)(src + u * 8);
}

// ------------- message' = relu(binput + sum_j msgW[bgraph[e][j]]) -------------
__global__ __launch_bounds__(256) void k_gather_relu(
    const int* __restrict__ bgraph, const bf16s* __restrict__ msgW,
    const bf16s* __restrict__ binput, bf16s* __restrict__ out) {
  const int tid = threadIdx.x;
  const int lane = tid & 31;
  const int e = blockIdx.x * 8 + (tid >> 5);
  int idx[MAXNB];
#pragma unroll
  for (int j = 0; j < MAXNB; ++j) idx[j] = bgraph[(size_t)e * MAXNB + j];
  ushort4 t[MAXNB];
#pragma unroll
  for (int j = 0; j < MAXNB; ++j)
    t[j] = *(const ushort4*)&msgW[(size_t)idx[j] * H + lane * 4];
  float acc[4];
  load4(&binput[(size_t)e * H + lane * 4], acc);
#pragma unroll
  for (int j = 0; j < MAXNB; ++j) {
    acc[0] += bf2f(t[j].x); acc[1] += bf2f(t[j].y);
    acc[2] += bf2f(t[j].z); acc[3] += bf2f(t[j].w);
  }
  acc[0] = fmaxf(acc[0], 0.f); acc[1] = fmaxf(acc[1], 0.f);
  acc[2] = fmaxf(acc[2], 0.f); acc[3] = fmaxf(acc[3], 0.f);
  store4(&out[(size_t)e * H + lane * 4], acc);
}

// atom_hiddens = relu(fatoms @ Wo[0:18] + sum_j msgWo[agraph[a][j]] + b_o)
__global__ __launch_bounds__(256) void k_atoms(
    const float* __restrict__ fatoms, const int* __restrict__ agraph,
    const bf16s* __restrict__ msgWo, const float* __restrict__ Wo,
    const float* __restrict__ bo, float* __restrict__ atomh) {
  __shared__ float Wl[AFD * H];
  const int tid = threadIdx.x;
  for (int i = tid; i < AFD * H; i += 256) Wl[i] = Wo[i];
  __syncthreads();
  const int lane = tid & 31;
  const int a = blockIdx.x * 8 + (tid >> 5);
  int idx[MAXNB];
#pragma unroll
  for (int j = 0; j < MAXNB; ++j) idx[j] = agraph[(size_t)a * MAXNB + j];
  ushort4 t[MAXNB];
#pragma unroll
  for (int j = 0; j < MAXNB; ++j)
    t[j] = *(const ushort4*)&msgWo[(size_t)idx[j] * H + lane * 4];
  float4 b = ((const float4*)bo)[lane];
  float acc[4] = {b.x, b.y, b.z, b.w};
#pragma unroll
  for (int k = 0; k < AFD; ++k) {
    float f = fatoms[(size_t)a * AFD + k];
    float4 w = *(const float4*)&Wl[k * H + lane * 4];
    acc[0] = fmaf(f, w.x, acc[0]); acc[1] = fmaf(f, w.y, acc[1]);
    acc[2] = fmaf(f, w.z, acc[2]); acc[3] = fmaf(f, w.w, acc[3]);
  }
#pragma unroll
  for (int j = 0; j < MAXNB; ++j) {
    acc[0] += bf2f(t[j].x); acc[1] += bf2f(t[j].y);
    acc[2] += bf2f(t[j].z); acc[3] += bf2f(t[j].w);
  }
  float r[4] = {fmaxf(acc[0], 0.f), fmaxf(acc[1], 0.f),
                fmaxf(acc[2], 0.f), fmaxf(acc[3], 0.f)};
  *(float4*)&atomh[(size_t)a * H + lane * 4] = make_float4(r[0], r[1], r[2], r[3]);
}

// ---------------- segment mean pool ----------------
__global__ void k_pool(const float* __restrict__ atomh,
                       const int* __restrict__ sstart, const int* __restrict__ slen,
                       float* __restrict__ out) {
  const int m = blockIdx.x;
  const int c = threadIdx.x;
  const int s = sstart[m];
  const int L = slen[m];
  float sum = 0.f;
  for (int i = 0; i < L; ++i) sum += atomh[(size_t)(s + i) * H + c];
  out[m * H + c] = sum / (float)L;
}

extern "C" void kernel_launch(void* const* d_in, const int* in_sizes, int n_in,
                              void* d_out, int out_size, void* d_ws, size_t ws_size,
                              hipStream_t stream) {
  const float* fatoms = (const float*)d_in[0];
  const float* fbonds = (const float*)d_in[1];
  const int* agraph = (const int*)d_in[2];
  const int* bgraph = (const int*)d_in[3];
  const int* sstart = (const int*)d_in[4];
  const int* slen = (const int*)d_in[5];
  const float* Wi = (const float*)d_in[6];
  const float* Wh = (const float*)d_in[7];
  const float* Wo = (const float*)d_in[8];
  const float* bo = (const float*)d_in[9];
  float* out = (float*)d_out;

  const size_t EH = (size_t)EDGES * H;
  bf16s* binput = (bf16s*)d_ws;          // [E,H] bf16, 51.2 MB
  bf16s* message = binput + EH;          // [E,H] bf16
  bf16s* msgW = message + EH;            // [E,H] bf16
  float* atomh = (float*)d_ws;           // overlays binput (dead after last gather)
  bf16s* wt_h = (bf16s*)d_out;           // stashed in d_out; k_pool overwrites later
  bf16s* wt_o = wt_h + H * H;

  k_binput<<<EDGES / 8 + 2, 256, 0, stream>>>(fbonds, Wi, binput, message,
                                              Wh, Wo, wt_h, wt_o);
  for (int d = 0; d < 5; ++d) {
    k_gemm_mfma<<<EDGES / 64, 256, 0, stream>>>(message, wt_h, msgW);
    k_gather_relu<<<EDGES / 8, 256, 0, stream>>>(bgraph, msgW, binput, message);
  }
  k_gemm_mfma<<<EDGES / 64, 256, 0, stream>>>(message, wt_o, msgW);
  k_atoms<<<NATOMS / 8, 256, 0, stream>>>(fatoms, agraph, msgW, Wo, bo, atomh);
  k_pool<<<NMOLS, H, 0, stream>>>(atomh, sstart, slen, out);
}

// Round 8
// 952.093 us; speedup vs baseline: 1.2644x; 1.2644x over previous
//
#include <hip/hip_runtime.h>

#define EDGES 200000
#define NATOMS 100000
#define NMOLS 2000
#define H 128
#define MAXNB 15
#define AFD 18
#define INFD 23
#define LROW 136  // LDS A-tile row stride (bf16): +8 pad, 16B-aligned rows, 2-way banks

typedef unsigned short bf16s;
typedef __attribute__((ext_vector_type(8))) short short8;
typedef __attribute__((ext_vector_type(4))) float f32x4;

__device__ inline float bf2f(bf16s u) {
  union { unsigned int i; float f; } c; c.i = ((unsigned int)u) << 16; return c.f;
}
__device__ inline bf16s f2bf(float f) {
  union { float f; unsigned int i; } c; c.f = f;
  unsigned int lsb = (c.i >> 16) & 1u;
  c.i += 0x7fffu + lsb;              // round-to-nearest-even
  return (bf16s)(c.i >> 16);
}
__device__ inline void load4(const bf16s* p, float v[4]) {
  ushort4 t = *(const ushort4*)p;
  v[0] = bf2f(t.x); v[1] = bf2f(t.y); v[2] = bf2f(t.z); v[3] = bf2f(t.w);
}
__device__ inline void store4(bf16s* p, const float v[4]) {
  ushort4 t; t.x = f2bf(v[0]); t.y = f2bf(v[1]); t.z = f2bf(v[2]); t.w = f2bf(v[3]);
  *(ushort4*)p = t;
}

// ------- one-time: Wt[n][k] = bf16(W[k][n]) for W_h and W_o[AFD:,:] -------
__global__ __launch_bounds__(256) void k_wt(
    const float* __restrict__ Wh, const float* __restrict__ Wo,
    bf16s* __restrict__ wt_h, bf16s* __restrict__ wt_o) {
  const float* S = blockIdx.x ? (Wo + AFD * H) : Wh;
  bf16s* D = blockIdx.x ? wt_o : wt_h;
  for (int i = threadIdx.x; i < H * H; i += 256) {
    int k = i >> 7, n = i & 127;
    D[n * H + k] = f2bf(S[i]);
  }
}

// ---------------- binput = fbonds @ W_i ; message = relu(binput) ----------------
__global__ __launch_bounds__(256) void k_binput(
    const float* __restrict__ fbonds, const float* __restrict__ Wi,
    bf16s* __restrict__ binput, bf16s* __restrict__ message) {
  __shared__ float Wl[INFD * H];
  const int tid = threadIdx.x;
  for (int i = tid; i < INFD * H; i += 256) Wl[i] = Wi[i];
  __syncthreads();
  const int lane = tid & 31;
  const int e = blockIdx.x * 8 + (tid >> 5);
  const float* fb = &fbonds[(size_t)e * INFD];
  float acc[4] = {0.f, 0.f, 0.f, 0.f};
#pragma unroll
  for (int k = 0; k < INFD; ++k) {
    float f = fb[k];
    float4 w = *(const float4*)&Wl[k * H + lane * 4];
    acc[0] = fmaf(f, w.x, acc[0]); acc[1] = fmaf(f, w.y, acc[1]);
    acc[2] = fmaf(f, w.z, acc[2]); acc[3] = fmaf(f, w.w, acc[3]);
  }
  store4(&binput[(size_t)e * H + lane * 4], acc);
  float r[4] = {fmaxf(acc[0], 0.f), fmaxf(acc[1], 0.f),
                fmaxf(acc[2], 0.f), fmaxf(acc[3], 0.f)};
  store4(&message[(size_t)e * H + lane * 4], r);
}

// ------------- standalone C = A @ W (used once, for P1 = M1 @ Wh) -------------
__global__ __launch_bounds__(256) void k_gemm_mfma(
    const bf16s* __restrict__ A, const bf16s* __restrict__ Wt,
    bf16s* __restrict__ C) {
  const int wave = threadIdx.x >> 6;
  const int lane = threadIdx.x & 63;
  const int m = lane & 15;
  const int quad = lane >> 4;
  const int row0 = blockIdx.x * 64 + wave * 16;

  f32x4 acc[8];
#pragma unroll
  for (int i = 0; i < 8; ++i) acc[i] = (f32x4){0.f, 0.f, 0.f, 0.f};

  const bf16s* Ap = A + (size_t)(row0 + m) * H + quad * 8;
  const bf16s* Wp = Wt + (size_t)m * H + quad * 8;
#pragma unroll
  for (int kk = 0; kk < 4; ++kk) {
    short8 af = *(const short8*)(Ap + kk * 32);
#pragma unroll
    for (int nt = 0; nt < 8; ++nt) {
      short8 bfr = *(const short8*)(Wp + (size_t)(nt * 16) * H + kk * 32);
      acc[nt] = __builtin_amdgcn_mfma_f32_16x16x32_bf16(af, bfr, acc[nt], 0, 0, 0);
    }
  }
  const int rbase = row0 + quad * 4;
#pragma unroll
  for (int nt = 0; nt < 8; ++nt) {
#pragma unroll
    for (int i = 0; i < 4; ++i) {
      C[(size_t)(rbase + i) * H + nt * 16 + m] = f2bf(acc[nt][i]);
    }
  }
}

// ---- fused depth step: Pout = (relu(binput + sum_j P[bgraph[e][j]])) @ Wt ----
// Wave-private: each wave owns 16 edges; gather->LDS tile; s_waitcnt only
// (NO __syncthreads -- waves never couple); then 32 MFMA + scalar C stores.
__global__ __launch_bounds__(256) void k_fused(
    const int* __restrict__ bgraph, const bf16s* __restrict__ P,
    const bf16s* __restrict__ binput, const bf16s* __restrict__ Wt,
    bf16s* __restrict__ Pout) {
  __shared__ bf16s Am[4][16 * LROW];
  const int tid = threadIdx.x;
  const int wave = tid >> 6;
  const int lane = tid & 63;
  bf16s* Aw = Am[wave];
  const int ebase = (blockIdx.x * 4 + wave) * 16;

  // gather phase: 8 rounds x 2 edges; 32 lanes/edge, 8 B/lane (R5 pattern)
  const int sub = lane >> 5;
  const int col = lane & 31;
  for (int r = 0; r < 8; ++r) {
    const int erow = r * 2 + sub;
    const int e = ebase + erow;
    int idx[MAXNB];
#pragma unroll
    for (int j = 0; j < MAXNB; ++j) idx[j] = bgraph[(size_t)e * MAXNB + j];
    ushort4 t[MAXNB];
#pragma unroll
    for (int j = 0; j < MAXNB; ++j)
      t[j] = *(const ushort4*)&P[(size_t)idx[j] * H + col * 4];
    float acc[4];
    load4(&binput[(size_t)e * H + col * 4], acc);
#pragma unroll
    for (int j = 0; j < MAXNB; ++j) {
      acc[0] += bf2f(t[j].x); acc[1] += bf2f(t[j].y);
      acc[2] += bf2f(t[j].z); acc[3] += bf2f(t[j].w);
    }
    ushort4 mq;
    mq.x = f2bf(fmaxf(acc[0], 0.f)); mq.y = f2bf(fmaxf(acc[1], 0.f));
    mq.z = f2bf(fmaxf(acc[2], 0.f)); mq.w = f2bf(fmaxf(acc[3], 0.f));
    *(ushort4*)&Aw[erow * LROW + col * 4] = mq;
  }
  // wave-internal LDS drain; no block barrier
  asm volatile("s_waitcnt lgkmcnt(0)" ::: "memory");

  // MFMA phase: 16 rows x 128 cols, K=128
  const int mm = lane & 15;
  const int quad = lane >> 4;
  f32x4 acc[8];
#pragma unroll
  for (int i = 0; i < 8; ++i) acc[i] = (f32x4){0.f, 0.f, 0.f, 0.f};
  const bf16s* Wp = Wt + (size_t)mm * H + quad * 8;
#pragma unroll
  for (int kk = 0; kk < 4; ++kk) {
    short8 af = *(const short8*)&Aw[mm * LROW + quad * 8 + kk * 32];
#pragma unroll
    for (int nt = 0; nt < 8; ++nt) {
      short8 bfr = *(const short8*)(Wp + (size_t)(nt * 16) * H + kk * 32);
      acc[nt] = __builtin_amdgcn_mfma_f32_16x16x32_bf16(af, bfr, acc[nt], 0, 0, 0);
    }
  }
  const int rbase = ebase + quad * 4;
#pragma unroll
  for (int nt = 0; nt < 8; ++nt) {
#pragma unroll
    for (int i = 0; i < 4; ++i) {
      Pout[(size_t)(rbase + i) * H + nt * 16 + mm] = f2bf(acc[nt][i]);
    }
  }
}

// atom_hiddens = relu(fatoms @ Wo[0:18] + sum_j msgWo[agraph[a][j]] + b_o)
__global__ __launch_bounds__(256) void k_atoms(
    const float* __restrict__ fatoms, const int* __restrict__ agraph,
    const bf16s* __restrict__ msgWo, const float* __restrict__ Wo,
    const float* __restrict__ bo, float* __restrict__ atomh) {
  __shared__ float Wl[AFD * H];
  const int tid = threadIdx.x;
  for (int i = tid; i < AFD * H; i += 256) Wl[i] = Wo[i];
  __syncthreads();
  const int lane = tid & 31;
  const int a = blockIdx.x * 8 + (tid >> 5);
  int idx[MAXNB];
#pragma unroll
  for (int j = 0; j < MAXNB; ++j) idx[j] = agraph[(size_t)a * MAXNB + j];
  ushort4 t[MAXNB];
#pragma unroll
  for (int j = 0; j < MAXNB; ++j)
    t[j] = *(const ushort4*)&msgWo[(size_t)idx[j] * H + lane * 4];
  float4 b = ((const float4*)bo)[lane];
  float acc[4] = {b.x, b.y, b.z, b.w};
#pragma unroll
  for (int k = 0; k < AFD; ++k) {
    float f = fatoms[(size_t)a * AFD + k];
    float4 w = *(const float4*)&Wl[k * H + lane * 4];
    acc[0] = fmaf(f, w.x, acc[0]); acc[1] = fmaf(f, w.y, acc[1]);
    acc[2] = fmaf(f, w.z, acc[2]); acc[3] = fmaf(f, w.w, acc[3]);
  }
#pragma unroll
  for (int j = 0; j < MAXNB; ++j) {
    acc[0] += bf2f(t[j].x); acc[1] += bf2f(t[j].y);
    acc[2] += bf2f(t[j].z); acc[3] += bf2f(t[j].w);
  }
  float r[4] = {fmaxf(acc[0], 0.f), fmaxf(acc[1], 0.f),
                fmaxf(acc[2], 0.f), fmaxf(acc[3], 0.f)};
  *(float4*)&atomh[(size_t)a * H + lane * 4] = make_float4(r[0], r[1], r[2], r[3]);
}

// ---------------- segment mean pool ----------------
__global__ void k_pool(const float* __restrict__ atomh,
                       const int* __restrict__ sstart, const int* __restrict__ slen,
                       float* __restrict__ out) {
  const int m = blockIdx.x;
  const int c = threadIdx.x;
  const int s = sstart[m];
  const int L = slen[m];
  float sum = 0.f;
  for (int i = 0; i < L; ++i) sum += atomh[(size_t)(s + i) * H + c];
  out[m * H + c] = sum / (float)L;
}

extern "C" void kernel_launch(void* const* d_in, const int* in_sizes, int n_in,
                              void* d_out, int out_size, void* d_ws, size_t ws_size,
                              hipStream_t stream) {
  const float* fatoms = (const float*)d_in[0];
  const float* fbonds = (const float*)d_in[1];
  const int* agraph = (const int*)d_in[2];
  const int* bgraph = (const int*)d_in[3];
  const int* sstart = (const int*)d_in[4];
  const int* slen = (const int*)d_in[5];
  const float* Wi = (const float*)d_in[6];
  const float* Wh = (const float*)d_in[7];
  const float* Wo = (const float*)d_in[8];
  const float* bo = (const float*)d_in[9];
  float* out = (float*)d_out;

  const size_t EH = (size_t)EDGES * H;
  bf16s* B0 = (bf16s*)d_ws;      // binput [E,H] bf16, 51.2 MB
  bf16s* B1 = B0 + EH;           // ping
  bf16s* B2 = B1 + EH;           // pong
  float* atomh = (float*)B0;     // overlays binput (dead after last fused step)
  bf16s* wt_h = (bf16s*)d_out;   // stashed in d_out; k_pool overwrites later
  bf16s* wt_o = wt_h + H * H;

  k_wt<<<2, 256, 0, stream>>>(Wh, Wo, wt_h, wt_o);
  k_binput<<<EDGES / 8, 256, 0, stream>>>(fbonds, Wi, B0, B2);          // M1 -> B2
  k_gemm_mfma<<<EDGES / 64, 256, 0, stream>>>(B2, wt_h, B1);            // P1 -> B1
  k_fused<<<EDGES / 64, 256, 0, stream>>>(bgraph, B1, B0, wt_h, B2);    // P2
  k_fused<<<EDGES / 64, 256, 0, stream>>>(bgraph, B2, B0, wt_h, B1);    // P3
  k_fused<<<EDGES / 64, 256, 0, stream>>>(bgraph, B1, B0, wt_h, B2);    // P4
  k_fused<<<EDGES / 64, 256, 0, stream>>>(bgraph, B2, B0, wt_h, B1);    // P5
  k_fused<<<EDGES / 64, 256, 0, stream>>>(bgraph, B1, B0, wt_o, B2);    // P6o
  k_atoms<<<NATOMS / 8, 256, 0, stream>>>(fatoms, agraph, B2, Wo, bo, atomh);
  k_pool<<<NMOLS, H, 0, stream>>>(atomh, sstart, slen, out);
}

// Round 9
// 920.237 us; speedup vs baseline: 1.3082x; 1.0346x over previous
//
#include <hip/hip_runtime.h>

#define EDGES 200000
#define NATOMS 100000
#define NMOLS 2000
#define H 128
#define MAXNB 15
#define AFD 18
#define INFD 23
#define LROW 136  // LDS A-tile row stride (bf16): +8 pad, 16B-aligned rows, 2-way banks

typedef unsigned short bf16s;
typedef __attribute__((ext_vector_type(8))) short short8;
typedef __attribute__((ext_vector_type(4))) float f32x4;

__device__ inline float bf2f(bf16s u) {
  union { unsigned int i; float f; } c; c.i = ((unsigned int)u) << 16; return c.f;
}
__device__ inline bf16s f2bf(float f) {
  union { float f; unsigned int i; } c; c.f = f;
  unsigned int lsb = (c.i >> 16) & 1u;
  c.i += 0x7fffu + lsb;              // round-to-nearest-even
  return (bf16s)(c.i >> 16);
}
__device__ inline void load4(const bf16s* p, float v[4]) {
  ushort4 t = *(const ushort4*)p;
  v[0] = bf2f(t.x); v[1] = bf2f(t.y); v[2] = bf2f(t.z); v[3] = bf2f(t.w);
}
__device__ inline void store4(bf16s* p, const float v[4]) {
  ushort4 t; t.x = f2bf(v[0]); t.y = f2bf(v[1]); t.z = f2bf(v[2]); t.w = f2bf(v[3]);
  *(ushort4*)p = t;
}

// ------- one-time: Wt[n][k] = bf16(W[k][n]) for W_h and W_o[AFD:,:] -------
__global__ __launch_bounds__(256) void k_wt(
    const float* __restrict__ Wh, const float* __restrict__ Wo,
    bf16s* __restrict__ wt_h, bf16s* __restrict__ wt_o) {
  const float* S = blockIdx.x ? (Wo + AFD * H) : Wh;
  bf16s* D = blockIdx.x ? wt_o : wt_h;
  for (int i = threadIdx.x; i < H * H; i += 256) {
    int k = i >> 7, n = i & 127;
    D[n * H + k] = f2bf(S[i]);
  }
}

// Two-pass MFMA epilogue: 16x128 @ 128x128 from wave-private LDS tile.
// Halved accumulator live range (16 AGPRs) -> more resident waves.
__device__ inline void mfma_two_pass(const bf16s* Aw, const bf16s* __restrict__ Wt,
                                     bf16s* __restrict__ Pout, int ebase, int lane) {
  const int mm = lane & 15;
  const int quad = lane >> 4;
  const bf16s* Wp = Wt + (size_t)mm * H + quad * 8;
  const int rbase = ebase + quad * 4;
#pragma unroll 1
  for (int half = 0; half < 2; ++half) {
    f32x4 acc[4];
#pragma unroll
    for (int i = 0; i < 4; ++i) acc[i] = (f32x4){0.f, 0.f, 0.f, 0.f};
#pragma unroll
    for (int kk = 0; kk < 4; ++kk) {
      short8 af = *(const short8*)&Aw[mm * LROW + quad * 8 + kk * 32];
#pragma unroll
      for (int nt = 0; nt < 4; ++nt) {
        short8 bfr = *(const short8*)(Wp + (size_t)((half * 4 + nt) * 16) * H + kk * 32);
        acc[nt] = __builtin_amdgcn_mfma_f32_16x16x32_bf16(af, bfr, acc[nt], 0, 0, 0);
      }
    }
#pragma unroll
    for (int nt = 0; nt < 4; ++nt) {
#pragma unroll
      for (int i = 0; i < 4; ++i) {
        Pout[(size_t)(rbase + i) * H + (half * 4 + nt) * 16 + mm] = f2bf(acc[nt][i]);
      }
    }
  }
}

// ---- binput = fbonds @ W_i (stored); P1 = relu(binput) @ W_h, wave-private ----
__global__ __launch_bounds__(256) void k_binput_gemm(
    const float* __restrict__ fbonds, const float* __restrict__ Wi,
    const bf16s* __restrict__ wt_h, bf16s* __restrict__ binput,
    bf16s* __restrict__ P1) {
  __shared__ float Wl[INFD * H];
  __shared__ bf16s Am[4][16 * LROW];
  const int tid = threadIdx.x;
  for (int i = tid; i < INFD * H; i += 256) Wl[i] = Wi[i];
  __syncthreads();
  const int wave = tid >> 6;
  const int lane = tid & 63;
  bf16s* Aw = Am[wave];
  const int ebase = (blockIdx.x * 4 + wave) * 16;
  const int sub = lane >> 5;
  const int col = lane & 31;
  for (int r = 0; r < 8; ++r) {
    const int erow = r * 2 + sub;
    const int e = ebase + erow;
    const float* fb = &fbonds[(size_t)e * INFD];
    float acc[4] = {0.f, 0.f, 0.f, 0.f};
#pragma unroll
    for (int k = 0; k < INFD; ++k) {
      float f = fb[k];
      float4 w = *(const float4*)&Wl[k * H + col * 4];
      acc[0] = fmaf(f, w.x, acc[0]); acc[1] = fmaf(f, w.y, acc[1]);
      acc[2] = fmaf(f, w.z, acc[2]); acc[3] = fmaf(f, w.w, acc[3]);
    }
    store4(&binput[(size_t)e * H + col * 4], acc);
    ushort4 mq;
    mq.x = f2bf(fmaxf(acc[0], 0.f)); mq.y = f2bf(fmaxf(acc[1], 0.f));
    mq.z = f2bf(fmaxf(acc[2], 0.f)); mq.w = f2bf(fmaxf(acc[3], 0.f));
    *(ushort4*)&Aw[erow * LROW + col * 4] = mq;
  }
  asm volatile("s_waitcnt lgkmcnt(0)" ::: "memory");
  mfma_two_pass(Aw, wt_h, P1, ebase, lane);
}

// ---- fused depth step: Pout = (relu(binput + sum_j P[bgraph[e][j]])) @ Wt ----
// Wave-private: gather 16 edges -> LDS tile; s_waitcnt only (no block barrier);
// then two-pass MFMA.
__global__ __launch_bounds__(256) void k_fused(
    const int* __restrict__ bgraph, const bf16s* __restrict__ P,
    const bf16s* __restrict__ binput, const bf16s* __restrict__ Wt,
    bf16s* __restrict__ Pout) {
  __shared__ bf16s Am[4][16 * LROW];
  const int tid = threadIdx.x;
  const int wave = tid >> 6;
  const int lane = tid & 63;
  bf16s* Aw = Am[wave];
  const int ebase = (blockIdx.x * 4 + wave) * 16;

  const int sub = lane >> 5;
  const int col = lane & 31;
  for (int r = 0; r < 8; ++r) {
    const int erow = r * 2 + sub;
    const int e = ebase + erow;
    int idx[MAXNB];
#pragma unroll
    for (int j = 0; j < MAXNB; ++j) idx[j] = bgraph[(size_t)e * MAXNB + j];
    ushort4 t[MAXNB];
#pragma unroll
    for (int j = 0; j < MAXNB; ++j)
      t[j] = *(const ushort4*)&P[(size_t)idx[j] * H + col * 4];
    float acc[4];
    load4(&binput[(size_t)e * H + col * 4], acc);
#pragma unroll
    for (int j = 0; j < MAXNB; ++j) {
      acc[0] += bf2f(t[j].x); acc[1] += bf2f(t[j].y);
      acc[2] += bf2f(t[j].z); acc[3] += bf2f(t[j].w);
    }
    ushort4 mq;
    mq.x = f2bf(fmaxf(acc[0], 0.f)); mq.y = f2bf(fmaxf(acc[1], 0.f));
    mq.z = f2bf(fmaxf(acc[2], 0.f)); mq.w = f2bf(fmaxf(acc[3], 0.f));
    *(ushort4*)&Aw[erow * LROW + col * 4] = mq;
  }
  asm volatile("s_waitcnt lgkmcnt(0)" ::: "memory");
  mfma_two_pass(Aw, Wt, Pout, ebase, lane);
}

// atom_hiddens = relu(fatoms @ Wo[0:18] + sum_j msgWo[agraph[a][j]] + b_o)
__global__ __launch_bounds__(256) void k_atoms(
    const float* __restrict__ fatoms, const int* __restrict__ agraph,
    const bf16s* __restrict__ msgWo, const float* __restrict__ Wo,
    const float* __restrict__ bo, float* __restrict__ atomh) {
  __shared__ float Wl[AFD * H];
  const int tid = threadIdx.x;
  for (int i = tid; i < AFD * H; i += 256) Wl[i] = Wo[i];
  __syncthreads();
  const int lane = tid & 31;
  const int a = blockIdx.x * 8 + (tid >> 5);
  int idx[MAXNB];
#pragma unroll
  for (int j = 0; j < MAXNB; ++j) idx[j] = agraph[(size_t)a * MAXNB + j];
  ushort4 t[MAXNB];
#pragma unroll
  for (int j = 0; j < MAXNB; ++j)
    t[j] = *(const ushort4*)&msgWo[(size_t)idx[j] * H + lane * 4];
  float4 b = ((const float4*)bo)[lane];
  float acc[4] = {b.x, b.y, b.z, b.w};
#pragma unroll
  for (int k = 0; k < AFD; ++k) {
    float f = fatoms[(size_t)a * AFD + k];
    float4 w = *(const float4*)&Wl[k * H + lane * 4];
    acc[0] = fmaf(f, w.x, acc[0]); acc[1] = fmaf(f, w.y, acc[1]);
    acc[2] = fmaf(f, w.z, acc[2]); acc[3] = fmaf(f, w.w, acc[3]);
  }
#pragma unroll
  for (int j = 0; j < MAXNB; ++j) {
    acc[0] += bf2f(t[j].x); acc[1] += bf2f(t[j].y);
    acc[2] += bf2f(t[j].z); acc[3] += bf2f(t[j].w);
  }
  float r[4] = {fmaxf(acc[0], 0.f), fmaxf(acc[1], 0.f),
                fmaxf(acc[2], 0.f), fmaxf(acc[3], 0.f)};
  *(float4*)&atomh[(size_t)a * H + lane * 4] = make_float4(r[0], r[1], r[2], r[3]);
}

// ---------------- segment mean pool ----------------
__global__ void k_pool(const float* __restrict__ atomh,
                       const int* __restrict__ sstart, const int* __restrict__ slen,
                       float* __restrict__ out) {
  const int m = blockIdx.x;
  const int c = threadIdx.x;
  const int s = sstart[m];
  const int L = slen[m];
  float sum = 0.f;
  for (int i = 0; i < L; ++i) sum += atomh[(size_t)(s + i) * H + c];
  out[m * H + c] = sum / (float)L;
}

extern "C" void kernel_launch(void* const* d_in, const int* in_sizes, int n_in,
                              void* d_out, int out_size, void* d_ws, size_t ws_size,
                              hipStream_t stream) {
  const float* fatoms = (const float*)d_in[0];
  const float* fbonds = (const float*)d_in[1];
  const int* agraph = (const int*)d_in[2];
  const int* bgraph = (const int*)d_in[3];
  const int* sstart = (const int*)d_in[4];
  const int* slen = (const int*)d_in[5];
  const float* Wi = (const float*)d_in[6];
  const float* Wh = (const float*)d_in[7];
  const float* Wo = (const float*)d_in[8];
  const float* bo = (const float*)d_in[9];
  float* out = (float*)d_out;

  const size_t EH = (size_t)EDGES * H;
  bf16s* B0 = (bf16s*)d_ws;      // binput [E,H] bf16, 51.2 MB
  bf16s* B1 = B0 + EH;           // ping
  bf16s* B2 = B1 + EH;           // pong
  float* atomh = (float*)B0;     // overlays binput (dead after last fused step)
  bf16s* wt_h = (bf16s*)d_out;   // stashed in d_out; k_pool overwrites later
  bf16s* wt_o = wt_h + H * H;

  k_wt<<<2, 256, 0, stream>>>(Wh, Wo, wt_h, wt_o);
  k_binput_gemm<<<EDGES / 64, 256, 0, stream>>>(fbonds, Wi, wt_h, B0, B1);  // P1
  k_fused<<<EDGES / 64, 256, 0, stream>>>(bgraph, B1, B0, wt_h, B2);    // P2
  k_fused<<<EDGES / 64, 256, 0, stream>>>(bgraph, B2, B0, wt_h, B1);    // P3
  k_fused<<<EDGES / 64, 256, 0, stream>>>(bgraph, B1, B0, wt_h, B2);    // P4
  k_fused<<<EDGES / 64, 256, 0, stream>>>(bgraph, B2, B0, wt_h, B1);    // P5
  k_fused<<<EDGES / 64, 256, 0, stream>>>(bgraph, B1, B0, wt_o, B2);    // P6o
  k_atoms<<<NATOMS / 8, 256, 0, stream>>>(fatoms, agraph, B2, Wo, bo, atomh);
  k_pool<<<NMOLS, H, 0, stream>>>(atomh, sstart, slen, out);
}

// Round 10
// 915.885 us; speedup vs baseline: 1.3144x; 1.0048x over previous
//
#include <hip/hip_runtime.h>

#define EDGES 200000
#define NATOMS 100000
#define NMOLS 2000
#define H 128
#define MAXNB 15
#define AFD 18
#define INFD 23
#define LROW 136  // LDS A-tile row stride (bf16): +8 pad, 16B-aligned rows, 2-way banks

typedef unsigned short bf16s;
typedef __attribute__((ext_vector_type(8))) short short8;
typedef __attribute__((ext_vector_type(4))) float f32x4;

__device__ inline float bf2f(bf16s u) {
  union { unsigned int i; float f; } c; c.i = ((unsigned int)u) << 16; return c.f;
}
__device__ inline bf16s f2bf(float f) {
  union { float f; unsigned int i; } c; c.f = f;
  unsigned int lsb = (c.i >> 16) & 1u;
  c.i += 0x7fffu + lsb;              // round-to-nearest-even
  return (bf16s)(c.i >> 16);
}
__device__ inline void load4(const bf16s* p, float v[4]) {
  ushort4 t = *(const ushort4*)p;
  v[0] = bf2f(t.x); v[1] = bf2f(t.y); v[2] = bf2f(t.z); v[3] = bf2f(t.w);
}
__device__ inline void store4(bf16s* p, const float v[4]) {
  ushort4 t; t.x = f2bf(v[0]); t.y = f2bf(v[1]); t.z = f2bf(v[2]); t.w = f2bf(v[3]);
  *(ushort4*)p = t;
}

// ------- one-time: Wt[n][k] = bf16(W[k][n]) for W_h and W_o[AFD:,:] -------
__global__ __launch_bounds__(256) void k_wt(
    const float* __restrict__ Wh, const float* __restrict__ Wo,
    bf16s* __restrict__ wt_h, bf16s* __restrict__ wt_o) {
  const float* S = blockIdx.x ? (Wo + AFD * H) : Wh;
  bf16s* D = blockIdx.x ? wt_o : wt_h;
  for (int i = threadIdx.x; i < H * H; i += 256) {
    int k = i >> 7, n = i & 127;
    D[n * H + k] = f2bf(S[i]);
  }
}

// Two-pass MFMA epilogue: 16x128 @ 128x128 from wave-private LDS tile.
__device__ inline void mfma_two_pass(const bf16s* Aw, const bf16s* __restrict__ Wt,
                                     bf16s* __restrict__ Pout, int ebase, int lane) {
  const int mm = lane & 15;
  const int quad = lane >> 4;
  const bf16s* Wp = Wt + (size_t)mm * H + quad * 8;
  const int rbase = ebase + quad * 4;
#pragma unroll 1
  for (int half = 0; half < 2; ++half) {
    f32x4 acc[4];
#pragma unroll
    for (int i = 0; i < 4; ++i) acc[i] = (f32x4){0.f, 0.f, 0.f, 0.f};
#pragma unroll
    for (int kk = 0; kk < 4; ++kk) {
      short8 af = *(const short8*)&Aw[mm * LROW + quad * 8 + kk * 32];
#pragma unroll
      for (int nt = 0; nt < 4; ++nt) {
        short8 bfr = *(const short8*)(Wp + (size_t)((half * 4 + nt) * 16) * H + kk * 32);
        acc[nt] = __builtin_amdgcn_mfma_f32_16x16x32_bf16(af, bfr, acc[nt], 0, 0, 0);
      }
    }
#pragma unroll
    for (int nt = 0; nt < 4; ++nt) {
#pragma unroll
      for (int i = 0; i < 4; ++i) {
        Pout[(size_t)(rbase + i) * H + (half * 4 + nt) * 16 + mm] = f2bf(acc[nt][i]);
      }
    }
  }
}

// ---- binput = fbonds @ W_i (stored); P1 = relu(binput) @ W_h, wave-private ----
__global__ __launch_bounds__(256) void k_binput_gemm(
    const float* __restrict__ fbonds, const float* __restrict__ Wi,
    const bf16s* __restrict__ wt_h, bf16s* __restrict__ binput,
    bf16s* __restrict__ P1) {
  __shared__ float Wl[INFD * H];
  __shared__ bf16s Am[4][16 * LROW];
  const int tid = threadIdx.x;
  for (int i = tid; i < INFD * H; i += 256) Wl[i] = Wi[i];
  __syncthreads();
  const int wave = tid >> 6;
  const int lane = tid & 63;
  bf16s* Aw = Am[wave];
  const int ebase = (blockIdx.x * 4 + wave) * 16;
  const int sub = lane >> 5;
  const int col = lane & 31;
  for (int r = 0; r < 8; ++r) {
    const int erow = r * 2 + sub;
    const int e = ebase + erow;
    const float* fb = &fbonds[(size_t)e * INFD];
    float acc[4] = {0.f, 0.f, 0.f, 0.f};
#pragma unroll
    for (int k = 0; k < INFD; ++k) {
      float f = fb[k];
      float4 w = *(const float4*)&Wl[k * H + col * 4];
      acc[0] = fmaf(f, w.x, acc[0]); acc[1] = fmaf(f, w.y, acc[1]);
      acc[2] = fmaf(f, w.z, acc[2]); acc[3] = fmaf(f, w.w, acc[3]);
    }
    store4(&binput[(size_t)e * H + col * 4], acc);
    ushort4 mq;
    mq.x = f2bf(fmaxf(acc[0], 0.f)); mq.y = f2bf(fmaxf(acc[1], 0.f));
    mq.z = f2bf(fmaxf(acc[2], 0.f)); mq.w = f2bf(fmaxf(acc[3], 0.f));
    *(ushort4*)&Aw[erow * LROW + col * 4] = mq;
  }
  asm volatile("s_waitcnt lgkmcnt(0)" ::: "memory");
  mfma_two_pass(Aw, wt_h, P1, ebase, lane);
}

// ---- fused depth step: Pout = (relu(binput + sum_j P[bgraph[e][j]])) @ Wt ----
// Block = 128 (2 waves): many small blocks of differing ages per CU so some
// waves gather while others MFMA (breaks phase lockstep). Wave-private LDS,
// no block barrier.
__global__ __launch_bounds__(128) void k_fused(
    const int* __restrict__ bgraph, const bf16s* __restrict__ P,
    const bf16s* __restrict__ binput, const bf16s* __restrict__ Wt,
    bf16s* __restrict__ Pout) {
  __shared__ bf16s Am[2][16 * LROW];
  const int tid = threadIdx.x;
  const int wave = tid >> 6;
  const int lane = tid & 63;
  bf16s* Aw = Am[wave];
  const int ebase = (blockIdx.x * 2 + wave) * 16;

  const int sub = lane >> 5;
  const int col = lane & 31;
  for (int r = 0; r < 8; ++r) {
    const int erow = r * 2 + sub;
    const int e = ebase + erow;
    int idx[MAXNB];
#pragma unroll
    for (int j = 0; j < MAXNB; ++j) idx[j] = bgraph[(size_t)e * MAXNB + j];
    ushort4 t[MAXNB];
#pragma unroll
    for (int j = 0; j < MAXNB; ++j)
      t[j] = *(const ushort4*)&P[(size_t)idx[j] * H + col * 4];
    float acc[4];
    load4(&binput[(size_t)e * H + col * 4], acc);
#pragma unroll
    for (int j = 0; j < MAXNB; ++j) {
      acc[0] += bf2f(t[j].x); acc[1] += bf2f(t[j].y);
      acc[2] += bf2f(t[j].z); acc[3] += bf2f(t[j].w);
    }
    ushort4 mq;
    mq.x = f2bf(fmaxf(acc[0], 0.f)); mq.y = f2bf(fmaxf(acc[1], 0.f));
    mq.z = f2bf(fmaxf(acc[2], 0.f)); mq.w = f2bf(fmaxf(acc[3], 0.f));
    *(ushort4*)&Aw[erow * LROW + col * 4] = mq;
  }
  asm volatile("s_waitcnt lgkmcnt(0)" ::: "memory");
  mfma_two_pass(Aw, Wt, Pout, ebase, lane);
}

// atom_hiddens = relu(fatoms @ Wo[0:18] + sum_j msgWo[agraph[a][j]] + b_o)
__global__ __launch_bounds__(256) void k_atoms(
    const float* __restrict__ fatoms, const int* __restrict__ agraph,
    const bf16s* __restrict__ msgWo, const float* __restrict__ Wo,
    const float* __restrict__ bo, float* __restrict__ atomh) {
  __shared__ float Wl[AFD * H];
  const int tid = threadIdx.x;
  for (int i = tid; i < AFD * H; i += 256) Wl[i] = Wo[i];
  __syncthreads();
  const int lane = tid & 31;
  const int a = blockIdx.x * 8 + (tid >> 5);
  int idx[MAXNB];
#pragma unroll
  for (int j = 0; j < MAXNB; ++j) idx[j] = agraph[(size_t)a * MAXNB + j];
  ushort4 t[MAXNB];
#pragma unroll
  for (int j = 0; j < MAXNB; ++j)
    t[j] = *(const ushort4*)&msgWo[(size_t)idx[j] * H + lane * 4];
  float4 b = ((const float4*)bo)[lane];
  float acc[4] = {b.x, b.y, b.z, b.w};
#pragma unroll
  for (int k = 0; k < AFD; ++k) {
    float f = fatoms[(size_t)a * AFD + k];
    float4 w = *(const float4*)&Wl[k * H + lane * 4];
    acc[0] = fmaf(f, w.x, acc[0]); acc[1] = fmaf(f, w.y, acc[1]);
    acc[2] = fmaf(f, w.z, acc[2]); acc[3] = fmaf(f, w.w, acc[3]);
  }
#pragma unroll
  for (int j = 0; j < MAXNB; ++j) {
    acc[0] += bf2f(t[j].x); acc[1] += bf2f(t[j].y);
    acc[2] += bf2f(t[j].z); acc[3] += bf2f(t[j].w);
  }
  float r[4] = {fmaxf(acc[0], 0.f), fmaxf(acc[1], 0.f),
                fmaxf(acc[2], 0.f), fmaxf(acc[3], 0.f)};
  *(float4*)&atomh[(size_t)a * H + lane * 4] = make_float4(r[0], r[1], r[2], r[3]);
}

// ---------------- segment mean pool ----------------
__global__ void k_pool(const float* __restrict__ atomh,
                       const int* __restrict__ sstart, const int* __restrict__ slen,
                       float* __restrict__ out) {
  const int m = blockIdx.x;
  const int c = threadIdx.x;
  const int s = sstart[m];
  const int L = slen[m];
  float sum = 0.f;
  for (int i = 0; i < L; ++i) sum += atomh[(size_t)(s + i) * H + c];
  out[m * H + c] = sum / (float)L;
}

extern "C" void kernel_launch(void* const* d_in, const int* in_sizes, int n_in,
                              void* d_out, int out_size, void* d_ws, size_t ws_size,
                              hipStream_t stream) {
  const float* fatoms = (const float*)d_in[0];
  const float* fbonds = (const float*)d_in[1];
  const int* agraph = (const int*)d_in[2];
  const int* bgraph = (const int*)d_in[3];
  const int* sstart = (const int*)d_in[4];
  const int* slen = (const int*)d_in[5];
  const float* Wi = (const float*)d_in[6];
  const float* Wh = (const float*)d_in[7];
  const float* Wo = (const float*)d_in[8];
  const float* bo = (const float*)d_in[9];
  float* out = (float*)d_out;

  const size_t EH = (size_t)EDGES * H;
  bf16s* B0 = (bf16s*)d_ws;      // binput [E,H] bf16, 51.2 MB
  bf16s* B1 = B0 + EH;           // ping
  bf16s* B2 = B1 + EH;           // pong
  float* atomh = (float*)B0;     // overlays binput (dead after last fused step)
  bf16s* wt_h = (bf16s*)d_out;   // stashed in d_out; k_pool overwrites later
  bf16s* wt_o = wt_h + H * H;

  k_wt<<<2, 256, 0, stream>>>(Wh, Wo, wt_h, wt_o);
  k_binput_gemm<<<EDGES / 64, 256, 0, stream>>>(fbonds, Wi, wt_h, B0, B1);  // P1
  k_fused<<<EDGES / 32, 128, 0, stream>>>(bgraph, B1, B0, wt_h, B2);    // P2
  k_fused<<<EDGES / 32, 128, 0, stream>>>(bgraph, B2, B0, wt_h, B1);    // P3
  k_fused<<<EDGES / 32, 128, 0, stream>>>(bgraph, B1, B0, wt_h, B2);    // P4
  k_fused<<<EDGES / 32, 128, 0, stream>>>(bgraph, B2, B0, wt_h, B1);    // P5
  k_fused<<<EDGES / 32, 128, 0, stream>>>(bgraph, B1, B0, wt_o, B2);    // P6o
  k_atoms<<<NATOMS / 8, 256, 0, stream>>>(fatoms, agraph, B2, Wo, bo, atomh);
  k_pool<<<NMOLS, H, 0, stream>>>(atomh, sstart, slen, out);
}